// Round 4
// baseline (179.454 us; speedup 1.0000x reference)
//
#include <hip/hip_runtime.h>
#include <hip/hip_bf16.h>

// Joiner: logits[n,t,u,v] = sum_d tanh(enc[n,t,d]+dec[n,u,d]) * W[v,d] + b[v]
// N=8 T=200 U=100 D=512 V=500  -> GEMM M=160000, K=512, N=500 (padded 512)
//
// R3: BM=128 x BN=512, 512 threads (8 waves: 2 wm x 4 wn, wave tile 64x128,
// acc[4][8]). Halves B L2 traffic vs BM=64 (MFMA-bound: 1242 MFMA cyc vs
// 585 B-load cyc per CU-step) and halves barrier rounds. Direct-B
// global->VGPR, A tanh-staged in dbuf LDS (1 barrier/K-step), streaming
// epilogue via 32-row LDS chunks.

#define NB 8
#define TT 200
#define UU 100
#define DD 512
#define VV 500
#define VP 512
#define BM 128
#define BK 32
#define KSTEPS 16          // 512/32
#define THREADS 512
#define LDA 40             // BK + 8 pad (ushort units, 80B row stride)
#define MROWS (NB*TT*UU)   // 160000
#define MBLOCKS (MROWS/BM) // 1250

typedef __attribute__((ext_vector_type(4))) float  f32x4;
typedef __attribute__((ext_vector_type(8))) short  s16x8;

__device__ __forceinline__ unsigned short f2bf(float f) {
    unsigned int u = __builtin_bit_cast(unsigned int, f);
    u = (u + 0x7FFFu + ((u >> 16) & 1u)) >> 16;   // round-to-nearest-even
    return (unsigned short)u;
}

__device__ __forceinline__ float fast_tanh(float x) {
    float e = __expf(2.0f * x);
    return 1.0f - 2.0f * __builtin_amdgcn_rcpf(e + 1.0f);
}

// ---- prep: W (500x512 f32) -> bf16, padded to 512 rows, tiled [kc][v][32] ----
__global__ void prep_w(const float* __restrict__ W, unsigned short* __restrict__ Wt) {
    int idx = blockIdx.x * 256 + threadIdx.x;   // 0 .. 512*512-1
    int k = idx & 511;
    int v = idx >> 9;
    float val = (v < VV) ? W[v * DD + k] : 0.0f;
    Wt[(k >> 5) * (VP * BK) + v * BK + (k & 31)] = f2bf(val);
}

__global__ __launch_bounds__(THREADS, 2) void joiner_kernel(
    const float* __restrict__ enc, const float* __restrict__ dec,
    const unsigned short* __restrict__ Wt, const float* __restrict__ bias,
    float* __restrict__ out)
{
    // union: K-loop A dbuf (2 x 10240 B) / epilogue chunk 32x500 f32 (64000 B)
    __shared__ __align__(16) char smem[64000];
    unsigned short* lA0 = (unsigned short*)smem;
    unsigned short* lA1 = (unsigned short*)(smem + BM * LDA * 2);

    const int tid  = threadIdx.x;
    const int mb   = blockIdx.x;
    const int lane = tid & 63;
    const int w    = tid >> 6;       // 0..7
    const int wm   = w >> 2;         // 0..1: 64-row half
    const int wn   = w & 3;          // 0..3: 128-col quarter
    const int lr   = lane & 15;
    const int lk   = lane >> 4;

    // staging: each thread produces 8 activations of one row
    const int srow = tid >> 2;          // 0..127
    const int sk   = (tid & 3) << 3;    // 0,8,16,24

    int r   = mb * BM + srow;
    int n   = r / (TT * UU);
    int rem = r - n * (TT * UU);
    int t   = rem / UU;
    int u   = rem - t * UU;
    const float* ep = enc + (n * TT + t) * DD + sk;
    const float* dp = dec + (n * UU + u) * DD + sk;

    f32x4 e0, e1, d0, d1;

    // ---- stage kc=0 ----
    e0 = *(const f32x4*)(ep);     e1 = *(const f32x4*)(ep + 4);
    d0 = *(const f32x4*)(dp);     d1 = *(const f32x4*)(dp + 4);
    {
        s16x8 av;
        #pragma unroll
        for (int j = 0; j < 4; ++j) av[j]     = (short)f2bf(fast_tanh(e0[j] + d0[j]));
        #pragma unroll
        for (int j = 0; j < 4; ++j) av[4 + j] = (short)f2bf(fast_tanh(e1[j] + d1[j]));
        *(s16x8*)(&lA0[srow * LDA + sk]) = av;
    }
    // ---- prefetch kc=1 into regs ----
    e0 = *(const f32x4*)(ep + BK);     e1 = *(const f32x4*)(ep + BK + 4);
    d0 = *(const f32x4*)(dp + BK);     d1 = *(const f32x4*)(dp + BK + 4);
    __syncthreads();

    f32x4 acc[4][8];
    #pragma unroll
    for (int m = 0; m < 4; ++m)
        #pragma unroll
        for (int f = 0; f < 8; ++f)
            acc[m][f] = (f32x4){0.f, 0.f, 0.f, 0.f};

    // per-thread B pointer into pre-tiled Wt: v = wn*128 + f*16 + lr, k = lk*8
    const unsigned short* wptr = Wt + (wn * 128 + lr) * BK + lk * 8;

    #pragma unroll 2
    for (int kc = 0; kc < KSTEPS; ++kc) {
        unsigned short* lCur = (kc & 1) ? lA1 : lA0;
        unsigned short* lNxt = (kc & 1) ? lA0 : lA1;

        // ---- B fragments: direct global->VGPR (L2/L1-hit, coalesced) ----
        s16x8 bF[8];
        #pragma unroll
        for (int f = 0; f < 8; ++f)
            bF[f] = *(const s16x8*)(wptr + kc * (VP * BK) + f * (16 * BK));

        // ---- A fragments from LDS (current buffer) ----
        s16x8 aF[4];
        #pragma unroll
        for (int m = 0; m < 4; ++m)
            aF[m] = *(const s16x8*)(&lCur[(wm * 64 + m * 16 + lr) * LDA + lk * 8]);

        // ---- stage next A tile, then prefetch the one after into regs ----
        if (kc < KSTEPS - 1) {
            s16x8 av;
            #pragma unroll
            for (int j = 0; j < 4; ++j) av[j]     = (short)f2bf(fast_tanh(e0[j] + d0[j]));
            #pragma unroll
            for (int j = 0; j < 4; ++j) av[4 + j] = (short)f2bf(fast_tanh(e1[j] + d1[j]));
            *(s16x8*)(&lNxt[srow * LDA + sk]) = av;
            if (kc < KSTEPS - 2) {
                const float* ep2 = ep + (kc + 2) * BK;
                const float* dp2 = dp + (kc + 2) * BK;
                e0 = *(const f32x4*)(ep2);     e1 = *(const f32x4*)(ep2 + 4);
                d0 = *(const f32x4*)(dp2);     d1 = *(const f32x4*)(dp2 + 4);
            }
        }

        // ---- 32 MFMAs ----
        __builtin_amdgcn_s_setprio(1);
        #pragma unroll
        for (int m = 0; m < 4; ++m)
            #pragma unroll
            for (int f = 0; f < 8; ++f)
                acc[m][f] = __builtin_amdgcn_mfma_f32_16x16x32_bf16(aF[m], bF[f], acc[m][f], 0, 0, 0);
        __builtin_amdgcn_s_setprio(0);

        __syncthreads();
    }

    // ---- epilogue: acc -> LDS 32-row chunks -> streaming f32x4 stores ----
    float bv[8];
    #pragma unroll
    for (int f = 0; f < 8; ++f) {
        int v = wn * 128 + f * 16 + lr;
        bv[f] = (v < VV) ? bias[v] : 0.0f;
    }

    float* lchunk = (float*)smem;                 // 32*500 f32 = 64000 B
    float* outbase = out + (long)mb * BM * VV;

    // chunk c covers block rows [32c, 32c+32): waves with wm == c>>1
    // contribute m = 2*(c&1) + {0,1}
    for (int c = 0; c < 4; ++c) {
        if (c > 0) __syncthreads();   // previous chunk fully streamed
        if (wm == (c >> 1)) {
            #pragma unroll
            for (int mm = 0; mm < 2; ++mm) {
                int m = 2 * (c & 1) + mm;
                #pragma unroll
                for (int f = 0; f < 8; ++f) {
                    int v = wn * 128 + f * 16 + lr;
                    if (v < VV) {
                        #pragma unroll
                        for (int q = 0; q < 4; ++q)
                            lchunk[(mm * 16 + lk * 4 + q) * VV + v] = acc[m][f][q] + bv[f];
                    }
                }
            }
        }
        __syncthreads();
        // 32 rows x 500 f32 = 16000 contiguous floats = 4000 f32x4
        float* dst = outbase + c * 32 * VV;
        #pragma unroll
        for (int i = 0; i < 8; ++i) {
            int c4 = i * THREADS + tid;
            if (c4 < 4000)
                *(f32x4*)(dst + c4 * 4) = *(const f32x4*)(lchunk + c4 * 4);
        }
    }
}

extern "C" void kernel_launch(void* const* d_in, const int* in_sizes, int n_in,
                              void* d_out, int out_size, void* d_ws, size_t ws_size,
                              hipStream_t stream) {
    const float* enc = (const float*)d_in[0];
    const float* dec = (const float*)d_in[1];
    const float* W   = (const float*)d_in[2];
    const float* b   = (const float*)d_in[3];
    float* out = (float*)d_out;
    unsigned short* Wt = (unsigned short*)d_ws;   // 512*512*2 = 512 KB

    prep_w<<<dim3((VP * DD) / 256), dim3(256), 0, stream>>>(W, Wt);
    joiner_kernel<<<dim3(MBLOCKS), dim3(THREADS), 0, stream>>>(enc, dec, Wt, b, out);
}

// Round 5
// 157.265 us; speedup vs baseline: 1.1411x; 1.1411x over previous
//
#include <hip/hip_runtime.h>
#include <hip/hip_bf16.h>

// Joiner: logits[n,t,u,v] = sum_d tanh(enc[n,t,d]+dec[n,u,d]) * W[v,d] + b[v]
// N=8 T=200 U=100 D=512 V=500  -> GEMM M=160000, K=512, N=500 (padded 512)
//
// R4: R2 skeleton (BM=64, 256 thr, dbuf-LDS A, 1 barrier/K-step, direct-B
// global->VGPR, streaming epilogue) with V SPLIT across blockIdx.y (BN=256):
// acc[4][4]=64 regs -> ~140 VGPR total -> 3 blocks/CU (launch_bounds(256,3))
// for cross-block phase overlap (R3 showed concurrency, not traffic, limits).

#define NB 8
#define TT 200
#define UU 100
#define DD 512
#define VV 500
#define VP 512
#define BM 64
#define BNB 256            // per-block V-columns
#define BK 32
#define KSTEPS 16          // 512/32
#define THREADS 256
#define LDA 40             // BK + 8 pad (ushort units, 80B row stride)
#define LCH 264            // epilogue chunk row stride in f32 (pad vs 256)
#define MROWS (NB*TT*UU)   // 160000
#define MBLOCKS (MROWS/BM) // 2500

typedef __attribute__((ext_vector_type(4))) float  f32x4;
typedef __attribute__((ext_vector_type(8))) short  s16x8;

__device__ __forceinline__ unsigned short f2bf(float f) {
    unsigned int u = __builtin_bit_cast(unsigned int, f);
    u = (u + 0x7FFFu + ((u >> 16) & 1u)) >> 16;   // round-to-nearest-even
    return (unsigned short)u;
}

__device__ __forceinline__ float fast_tanh(float x) {
    float e = __expf(2.0f * x);
    return 1.0f - 2.0f * __builtin_amdgcn_rcpf(e + 1.0f);
}

// ---- prep: W (500x512 f32) -> bf16, padded to 512 rows, tiled [kc][v][32] ----
__global__ void prep_w(const float* __restrict__ W, unsigned short* __restrict__ Wt) {
    int idx = blockIdx.x * 256 + threadIdx.x;   // 0 .. 512*512-1
    int k = idx & 511;
    int v = idx >> 9;
    float val = (v < VV) ? W[v * DD + k] : 0.0f;
    Wt[(k >> 5) * (VP * BK) + v * BK + (k & 31)] = f2bf(val);
}

__global__ __launch_bounds__(THREADS, 3) void joiner_kernel(
    const float* __restrict__ enc, const float* __restrict__ dec,
    const unsigned short* __restrict__ Wt, const float* __restrict__ bias,
    float* __restrict__ out)
{
    // union: K-loop A dbuf (2 x 5120 B) / epilogue chunk 16 x LCH f32 (16896 B)
    __shared__ __align__(16) char smem[16 * LCH * 4];
    unsigned short* lA0 = (unsigned short*)smem;
    unsigned short* lA1 = (unsigned short*)(smem + BM * LDA * 2);

    const int tid  = threadIdx.x;
    const int mb   = blockIdx.x;
    const int vb   = blockIdx.y;     // 0,1: which 256-col slab of V
    const int lane = tid & 63;
    const int wn   = tid >> 6;       // 0..3: 64-col quarter of the slab
    const int lr   = lane & 15;
    const int lk   = lane >> 4;

    // staging: each thread produces 8 activations of one row
    const int srow = tid >> 2;          // 0..63
    const int sk   = (tid & 3) << 3;    // 0,8,16,24

    int r   = mb * BM + srow;
    int n   = r / (TT * UU);
    int rem = r - n * (TT * UU);
    int t   = rem / UU;
    int u   = rem - t * UU;
    const float* ep = enc + (n * TT + t) * DD + sk;
    const float* dp = dec + (n * UU + u) * DD + sk;

    f32x4 e0, e1, d0, d1;

    // ---- stage kc=0 ----
    e0 = *(const f32x4*)(ep);     e1 = *(const f32x4*)(ep + 4);
    d0 = *(const f32x4*)(dp);     d1 = *(const f32x4*)(dp + 4);
    {
        s16x8 av;
        #pragma unroll
        for (int j = 0; j < 4; ++j) av[j]     = (short)f2bf(fast_tanh(e0[j] + d0[j]));
        #pragma unroll
        for (int j = 0; j < 4; ++j) av[4 + j] = (short)f2bf(fast_tanh(e1[j] + d1[j]));
        *(s16x8*)(&lA0[srow * LDA + sk]) = av;
    }
    // ---- prefetch kc=1 into regs ----
    e0 = *(const f32x4*)(ep + BK);     e1 = *(const f32x4*)(ep + BK + 4);
    d0 = *(const f32x4*)(dp + BK);     d1 = *(const f32x4*)(dp + BK + 4);
    __syncthreads();

    f32x4 acc[4][4];
    #pragma unroll
    for (int m = 0; m < 4; ++m)
        #pragma unroll
        for (int f = 0; f < 4; ++f)
            acc[m][f] = (f32x4){0.f, 0.f, 0.f, 0.f};

    // per-thread B pointer: v = vb*256 + wn*64 + f*16 + lr, k = lk*8
    const unsigned short* wptr = Wt + (vb * BNB + wn * 64 + lr) * BK + lk * 8;

    for (int kc = 0; kc < KSTEPS; ++kc) {
        unsigned short* lCur = (kc & 1) ? lA1 : lA0;
        unsigned short* lNxt = (kc & 1) ? lA0 : lA1;

        // ---- B fragments: direct global->VGPR (L1/L2-hit, coalesced) ----
        s16x8 bF[4];
        #pragma unroll
        for (int f = 0; f < 4; ++f)
            bF[f] = *(const s16x8*)(wptr + kc * (VP * BK) + f * (16 * BK));

        // ---- A fragments from LDS (current buffer): all 64 rows ----
        s16x8 aF[4];
        #pragma unroll
        for (int m = 0; m < 4; ++m)
            aF[m] = *(const s16x8*)(&lCur[(m * 16 + lr) * LDA + lk * 8]);

        // ---- stage next A tile, then prefetch the one after into regs ----
        if (kc < KSTEPS - 1) {
            s16x8 av;
            #pragma unroll
            for (int j = 0; j < 4; ++j) av[j]     = (short)f2bf(fast_tanh(e0[j] + d0[j]));
            #pragma unroll
            for (int j = 0; j < 4; ++j) av[4 + j] = (short)f2bf(fast_tanh(e1[j] + d1[j]));
            *(s16x8*)(&lNxt[srow * LDA + sk]) = av;
            if (kc < KSTEPS - 2) {
                const float* ep2 = ep + (kc + 2) * BK;
                const float* dp2 = dp + (kc + 2) * BK;
                e0 = *(const f32x4*)(ep2);     e1 = *(const f32x4*)(ep2 + 4);
                d0 = *(const f32x4*)(dp2);     d1 = *(const f32x4*)(dp2 + 4);
            }
        }

        // ---- 16 MFMAs ----
        __builtin_amdgcn_s_setprio(1);
        #pragma unroll
        for (int m = 0; m < 4; ++m)
            #pragma unroll
            for (int f = 0; f < 4; ++f)
                acc[m][f] = __builtin_amdgcn_mfma_f32_16x16x32_bf16(aF[m], bF[f], acc[m][f], 0, 0, 0);
        __builtin_amdgcn_s_setprio(0);

        __syncthreads();
    }

    // ---- epilogue: acc -> LDS 16-row chunks -> streaming f32x4 stores ----
    float bv[4];
    #pragma unroll
    for (int f = 0; f < 4; ++f) {
        int v = vb * BNB + wn * 64 + f * 16 + lr;
        bv[f] = (v < VV) ? bias[v] : 0.0f;
    }

    float* lchunk = (float*)smem;                 // 16 x LCH f32
    const int slabcols = (vb == 0) ? BNB : (VV - BNB);   // 256 or 244
    const int segmax   = slabcols >> 2;                   // 64 or 61
    float* outbase = out + (long)mb * BM * VV + vb * BNB;

    for (int c = 0; c < 4; ++c) {
        __syncthreads();   // LDS free (K-loop done / previous chunk streamed)
        // chunk c covers block rows [16c, 16c+16): every wave contributes
        // acc[c][*] into its 64-col slice
        #pragma unroll
        for (int f = 0; f < 4; ++f) {
            int vloc = wn * 64 + f * 16 + lr;
            #pragma unroll
            for (int q = 0; q < 4; ++q)
                lchunk[(lk * 4 + q) * LCH + vloc] = acc[c][f][q] + bv[f];
        }
        __syncthreads();
        // stream 16 rows x slabcols f32; per row a contiguous 1024/976 B run
        float* dst = outbase + c * 16 * VV;
        #pragma unroll
        for (int i = 0; i < 4; ++i) {
            int idx = i * THREADS + tid;        // 0..1023
            int row = idx >> 6;
            int seg = idx & 63;
            if (seg < segmax)
                *(f32x4*)(dst + row * VV + seg * 4) =
                    *(const f32x4*)(lchunk + row * LCH + seg * 4);
        }
    }
}

extern "C" void kernel_launch(void* const* d_in, const int* in_sizes, int n_in,
                              void* d_out, int out_size, void* d_ws, size_t ws_size,
                              hipStream_t stream) {
    const float* enc = (const float*)d_in[0];
    const float* dec = (const float*)d_in[1];
    const float* W   = (const float*)d_in[2];
    const float* b   = (const float*)d_in[3];
    float* out = (float*)d_out;
    unsigned short* Wt = (unsigned short*)d_ws;   // 512*512*2 = 512 KB

    prep_w<<<dim3((VP * DD) / 256), dim3(256), 0, stream>>>(W, Wt);
    joiner_kernel<<<dim3(MBLOCKS, 2), dim3(THREADS), 0, stream>>>(enc, dec, Wt, b, out);
}